// Round 1
// baseline (245.622 us; speedup 1.0000x reference)
//
#include <hip/hip_runtime.h>

typedef unsigned short u16;
typedef __attribute__((ext_vector_type(8))) short bf16x8;
typedef __attribute__((ext_vector_type(4))) float f32x4;

#define MFMA(a, b, c) __builtin_amdgcn_mfma_f32_16x16x32_bf16(a, b, c, 0, 0, 0)

#define STAGE16(g, l) __builtin_amdgcn_global_load_lds( \
    (const __attribute__((address_space(1))) void*)(g),  \
    (__attribute__((address_space(3))) void*)(l), 16, 0, 0)

__device__ __forceinline__ u16 f2bf(float f) {
  union { float f; unsigned u; } v; v.f = f;
  return (u16)((v.u + 0x7fffu + ((v.u >> 16) & 1u)) >> 16);
}

// ---------------------------------------------------------------- convert
// fp32 -> bf16 (RNE) for x, y, Wq, Wk, Wv, Wproj. 4 elems/thread.
__global__ __launch_bounds__(256) void convert_all(
    const float* __restrict__ x, const float* __restrict__ y,
    const float* __restrict__ wq, const float* __restrict__ wk,
    const float* __restrict__ wv, const float* __restrict__ wp,
    u16* __restrict__ xb, u16* __restrict__ yb,
    u16* __restrict__ wqb, u16* __restrict__ wkb,
    u16* __restrict__ wvb, u16* __restrict__ wpb)
{
  constexpr int G0 = 4096 * 768 / 4;        // x groups
  constexpr int G1 = G0 + 8192 * 768 / 4;   // + y groups
  constexpr int GW = 768 * 768 / 4;         // per-weight groups
  int g = blockIdx.x * 256 + threadIdx.x;
  const float* s; u16* d; int o;
  if      (g < G0)          { s = x;  d = xb;  o = g; }
  else if (g < G1)          { s = y;  d = yb;  o = g - G0; }
  else if (g < G1 + GW)     { s = wq; d = wqb; o = g - G1; }
  else if (g < G1 + 2*GW)   { s = wk; d = wkb; o = g - G1 - GW; }
  else if (g < G1 + 3*GW)   { s = wv; d = wvb; o = g - G1 - 2*GW; }
  else if (g < G1 + 4*GW)   { s = wp; d = wpb; o = g - G1 - 3*GW; }
  else return;
  float4 v = reinterpret_cast<const float4*>(s)[o];
  ushort4 r;
  r.x = f2bf(v.x); r.y = f2bf(v.y); r.z = f2bf(v.z); r.w = f2bf(v.w);
  reinterpret_cast<ushort4*>(d)[o] = r;
}

// ---------------------------------------------------------------- GEMM
// C = A @ W^T, A:[M,768] bf16 row-major, W:[768,768] bf16 row-major (both
// K-contiguous -> NT gemm). 128x128 tile, BK=64, 4 waves (2x2), each wave
// a 64x64 sub-tile of 4x4 16x16x32 MFMA frags.
// LDS tiles [128][64] bf16, staged via global_load_lds(16B) with the XOR
// chunk swizzle applied on the GLOBAL source (linear LDS dest, rule #21):
//   LDS[row][chunk] = G[row][chunk ^ (row&7)], 16B chunks.
// PROJ=false: fused Q/K/V (grid 960, runtime mode decode), bf16 scatter to
//   Q[B,H,Nx,64], K[B,H,Ny,64], Vt[B,H,64,Ny].
// PROJ=true: out-projection, fp32 + bias to d_out (grid 192).
template <bool PROJ>
__global__ __launch_bounds__(256) void gemm_k(
    const u16* __restrict__ A0, const u16* __restrict__ A1,
    const u16* __restrict__ W0, const u16* __restrict__ W1,
    const u16* __restrict__ W2,
    u16* __restrict__ Qb, u16* __restrict__ Kb, u16* __restrict__ Vtb,
    const float* __restrict__ bias, float* __restrict__ fout)
{
  __shared__ u16 sA[128 * 64];
  __shared__ u16 sB[128 * 64];

  int bid = blockIdx.x;
  const u16 *A, *W;
  int mode, mt, nt;
  if (PROJ)           { mode = 3; A = A0; W = W0; mt = bid / 6;        nt = bid % 6; }
  else if (bid < 192) { mode = 0; A = A0; W = W0; mt = bid / 6;        nt = bid % 6; }
  else if (bid < 576) { mode = 1; A = A1; W = W1; mt = (bid-192) / 6;  nt = (bid-192) % 6; }
  else                { mode = 2; A = A1; W = W2; mt = (bid-576) / 6;  nt = (bid-576) % 6; }

  const int tid = threadIdx.x;
  const int w = tid >> 6, l = tid & 63;
  const int wm = w >> 1, wn = w & 1;
  const int g = l >> 4, m = l & 15;

  const int mbase = mt * 128, nbase = nt * 128;

  // staging addressing: lane -> (row l>>3 of 8-row issue, 16B chunk l&7),
  // global chunk pre-swizzled so swizzled read sees linear data
  const int srow = l >> 3;
  const int schunk = ((l & 7) ^ srow) * 8;  // elements
  const u16* Ag = A + (size_t)(mbase + srow) * 768 + schunk;
  const u16* Wg = W + (size_t)(nbase + srow) * 768 + schunk;

  f32x4 acc[4][4] = {};

  for (int kt = 0; kt < 12; ++kt) {
    __syncthreads();
    const int ko = kt * 64;
#pragma unroll
    for (int i = 0; i < 4; ++i) {
      const int ri = (i * 4 + w) * 8;       // 8-row block this wave stages
      STAGE16(Ag + (size_t)ri * 768 + ko, (char*)sA + ri * 128);
      STAGE16(Wg + (size_t)ri * 768 + ko, (char*)sB + ri * 128);
    }
    __syncthreads();

    bf16x8 af[2][4], bfr[2][4];
#pragma unroll
    for (int c = 0; c < 2; ++c)
#pragma unroll
      for (int t = 0; t < 4; ++t) {
        const int ar = wm * 64 + t * 16 + m;
        const int br = wn * 64 + t * 16 + m;
        const int cp = ((c * 4 + g) ^ (l & 7)) * 16;  // swizzled 16B chunk
        af[c][t]  = *reinterpret_cast<const bf16x8*>((const char*)sA + ar * 128 + cp);
        bfr[c][t] = *reinterpret_cast<const bf16x8*>((const char*)sB + br * 128 + cp);
      }
#pragma unroll
    for (int c = 0; c < 2; ++c)
#pragma unroll
      for (int mi = 0; mi < 4; ++mi)
#pragma unroll
        for (int ni = 0; ni < 4; ++ni)
          acc[mi][ni] = MFMA(af[c][mi], bfr[c][ni], acc[mi][ni]);
  }

  // epilogue: C/D layout col = lane&15, row = (lane>>4)*4 + reg
  const int rowb = mbase + wm * 64 + g * 4;
  const int colb = nbase + wn * 64 + m;
#pragma unroll
  for (int mi = 0; mi < 4; ++mi) {
#pragma unroll
    for (int ni = 0; ni < 4; ++ni) {
      const int col = colb + ni * 16;
      const int h = col >> 6, d = col & 63;
      if constexpr (PROJ) {
#pragma unroll
        for (int r = 0; r < 4; ++r) {
          const int row = rowb + mi * 16 + r;
          fout[(size_t)row * 768 + col] = acc[mi][ni][r] + bias[col];
        }
      } else {
        if (mode == 0) {
#pragma unroll
          for (int r = 0; r < 4; ++r) {
            const int row = rowb + mi * 16 + r;
            const int b_ = row >> 10, n = row & 1023;
            Qb[((size_t)(b_ * 12 + h) * 1024 + n) * 64 + d] = f2bf(acc[mi][ni][r]);
          }
        } else if (mode == 1) {
#pragma unroll
          for (int r = 0; r < 4; ++r) {
            const int row = rowb + mi * 16 + r;
            const int b_ = row >> 11, n = row & 2047;
            Kb[((size_t)(b_ * 12 + h) * 2048 + n) * 64 + d] = f2bf(acc[mi][ni][r]);
          }
        } else {
          // Vt[B,H,64,Ny]: 4 regs are consecutive n -> one 8B store
          const int row = rowb + mi * 16;
          const int b_ = row >> 11, n = row & 2047;
          ushort4 pk;
          pk.x = f2bf(acc[mi][ni][0]); pk.y = f2bf(acc[mi][ni][1]);
          pk.z = f2bf(acc[mi][ni][2]); pk.w = f2bf(acc[mi][ni][3]);
          *reinterpret_cast<ushort4*>(Vtb + ((size_t)(b_ * 12 + h) * 64 + d) * 2048 + n) = pk;
        }
      }
    }
  }
}

// ---------------------------------------------------------------- attention
// Flash-style. Block = one (b,h) x 64 q-rows; 4 waves, 16 q-rows/wave.
// KVBLK=64 per iteration over Ny=2048. K/V read from global (L2-resident).
// Online softmax in exp2 domain, wave-parallel via shfl_xor over 16-lane
// groups (C-layout: col = lane&15, row = (lane>>4)*4 + reg).
__global__ __launch_bounds__(256) void attn_fwd(
    const u16* __restrict__ Qb, const u16* __restrict__ Kb,
    const u16* __restrict__ Vtb, u16* __restrict__ AOb)
{
  __shared__ u16 pS[4][16][72];  // per-wave P tile, +8 pad (bank spread)

  const int bid = blockIdx.x;
  const int bh = bid >> 4, qt = bid & 15;
  const int tid = threadIdx.x;
  const int w = tid >> 6, l = tid & 63;
  const int g = l >> 4, m = l & 15;

  // Q A-frags, held in registers for the whole kernel
  const u16* qrow = Qb + ((size_t)bh * 1024 + qt * 64 + w * 16 + m) * 64 + g * 8;
  const bf16x8 aq0 = *reinterpret_cast<const bf16x8*>(qrow);
  const bf16x8 aq1 = *reinterpret_cast<const bf16x8*>(qrow + 32);

  const u16* Kbh = Kb + (size_t)bh * 2048 * 64;
  const u16* Vbh = Vtb + (size_t)bh * 64 * 2048;

  f32x4 o[4] = {};
  float mrun[4], lrun[4];
#pragma unroll
  for (int r = 0; r < 4; ++r) { mrun[r] = -1e30f; lrun[r] = 0.f; }
  const float SC = 0.125f * 1.4426950408889634f;  // scale * log2(e)

  for (int kt = 0; kt < 32; ++kt) {
    const int kv0 = kt * 64;
    // S = Q @ K^T  (16 q x 64 kv per wave)
    f32x4 s[4] = {};
#pragma unroll
    for (int j = 0; j < 4; ++j) {
      const u16* kr = Kbh + (size_t)(kv0 + j * 16 + m) * 64 + g * 8;
      const bf16x8 bk0 = *reinterpret_cast<const bf16x8*>(kr);
      const bf16x8 bk1 = *reinterpret_cast<const bf16x8*>(kr + 32);
      s[j] = MFMA(aq0, bk0, s[j]);
      s[j] = MFMA(aq1, bk1, s[j]);
    }
    // online softmax (exp2 domain)
    float z[4][4], tmax[4], tsum[4];
#pragma unroll
    for (int r = 0; r < 4; ++r) tmax[r] = -1e30f;
#pragma unroll
    for (int j = 0; j < 4; ++j)
#pragma unroll
      for (int r = 0; r < 4; ++r) {
        z[j][r] = s[j][r] * SC;
        tmax[r] = fmaxf(tmax[r], z[j][r]);
      }
#pragma unroll
    for (int dd = 1; dd < 16; dd <<= 1)
#pragma unroll
      for (int r = 0; r < 4; ++r)
        tmax[r] = fmaxf(tmax[r], __shfl_xor(tmax[r], dd));
    float al[4];
#pragma unroll
    for (int r = 0; r < 4; ++r) {
      const float mn = fmaxf(mrun[r], tmax[r]);
      al[r] = exp2f(mrun[r] - mn);
      mrun[r] = mn;
      tsum[r] = 0.f;
    }
#pragma unroll
    for (int j = 0; j < 4; ++j)
#pragma unroll
      for (int r = 0; r < 4; ++r) {
        const float p = exp2f(z[j][r] - mrun[r]);
        z[j][r] = p;
        tsum[r] += p;
      }
#pragma unroll
    for (int dd = 1; dd < 16; dd <<= 1)
#pragma unroll
      for (int r = 0; r < 4; ++r)
        tsum[r] += __shfl_xor(tsum[r], dd);
#pragma unroll
    for (int r = 0; r < 4; ++r)
      lrun[r] = lrun[r] * al[r] + tsum[r];
#pragma unroll
    for (int jd = 0; jd < 4; ++jd) {
      f32x4 t = o[jd];
      t[0] *= al[0]; t[1] *= al[1]; t[2] *= al[2]; t[3] *= al[3];
      o[jd] = t;
    }
    // P: C-layout -> LDS -> A-frag layout (per-wave buffer, no barrier)
#pragma unroll
    for (int j = 0; j < 4; ++j)
#pragma unroll
      for (int r = 0; r < 4; ++r)
        pS[w][g * 4 + r][j * 16 + m] = f2bf(z[j][r]);
    const bf16x8 ap0 = *reinterpret_cast<const bf16x8*>(&pS[w][m][g * 8]);
    const bf16x8 ap1 = *reinterpret_cast<const bf16x8*>(&pS[w][m][32 + g * 8]);
    // O += P @ V  (B-frag = contiguous 16B from Vt rows)
#pragma unroll
    for (int jd = 0; jd < 4; ++jd) {
      const u16* vr = Vbh + (size_t)(jd * 16 + m) * 2048 + kv0 + g * 8;
      const bf16x8 bv0 = *reinterpret_cast<const bf16x8*>(vr);
      const bf16x8 bv1 = *reinterpret_cast<const bf16x8*>(vr + 32);
      o[jd] = MFMA(ap0, bv0, o[jd]);
      o[jd] = MFMA(ap1, bv1, o[jd]);
    }
  }
  // epilogue: O/l -> bf16 -> [B, Nx, H*64]
  const int b_ = bh / 12, h = bh % 12;
  const int q0 = qt * 64 + w * 16 + g * 4;
#pragma unroll
  for (int r = 0; r < 4; ++r) {
    const float rl = 1.f / lrun[r];
#pragma unroll
    for (int jd = 0; jd < 4; ++jd)
      AOb[((size_t)b_ * 1024 + q0 + r) * 768 + h * 64 + jd * 16 + m] =
          f2bf(o[jd][r] * rl);
  }
}

// ---------------------------------------------------------------- launch
extern "C" void kernel_launch(void* const* d_in, const int* in_sizes, int n_in,
                              void* d_out, int out_size, void* d_ws, size_t ws_size,
                              hipStream_t stream)
{
  const float* x  = (const float*)d_in[0];
  const float* y  = (const float*)d_in[1];
  const float* wq = (const float*)d_in[2];
  const float* wk = (const float*)d_in[3];
  const float* wv = (const float*)d_in[4];
  const float* wp = (const float*)d_in[5];
  const float* bp = (const float*)d_in[6];
  float* out = (float*)d_out;

  char* ws = (char*)d_ws;
  u16* xb  = (u16*)ws; ws += (size_t)4096 * 768 * 2;
  u16* yb  = (u16*)ws; ws += (size_t)8192 * 768 * 2;
  u16* wqb = (u16*)ws; ws += (size_t)768 * 768 * 2;
  u16* wkb = (u16*)ws; ws += (size_t)768 * 768 * 2;
  u16* wvb = (u16*)ws; ws += (size_t)768 * 768 * 2;
  u16* wpb = (u16*)ws; ws += (size_t)768 * 768 * 2;
  u16* Qb  = (u16*)ws; ws += (size_t)4096 * 768 * 2;
  u16* Kb  = (u16*)ws; ws += (size_t)8192 * 768 * 2;
  u16* Vtb = (u16*)ws; ws += (size_t)8192 * 768 * 2;
  u16* AOb = (u16*)ws; ws += (size_t)4096 * 768 * 2;

  convert_all<<<11520, 256, 0, stream>>>(x, y, wq, wk, wv, wp,
                                         xb, yb, wqb, wkb, wvb, wpb);
  gemm_k<false><<<960, 256, 0, stream>>>(xb, yb, wqb, wkb, wvb,
                                         Qb, Kb, Vtb, nullptr, nullptr);
  attn_fwd<<<768, 256, 0, stream>>>(Qb, Kb, Vtb, AOb);
  gemm_k<true><<<192, 256, 0, stream>>>(AOb, nullptr, wpb, nullptr, nullptr,
                                        nullptr, nullptr, nullptr, bp, out);
}

// Round 2
// 170.818 us; speedup vs baseline: 1.4379x; 1.4379x over previous
//
#include <hip/hip_runtime.h>

typedef unsigned short u16;
typedef __attribute__((ext_vector_type(8))) short bf16x8;
typedef __attribute__((ext_vector_type(4))) float f32x4;

#define MFMA(a, b, c) __builtin_amdgcn_mfma_f32_16x16x32_bf16(a, b, c, 0, 0, 0)

#define STAGE16(g, l) __builtin_amdgcn_global_load_lds( \
    (const __attribute__((address_space(1))) void*)(g),  \
    (__attribute__((address_space(3))) void*)(l), 16, 0, 0)

__device__ __forceinline__ u16 f2bf(float f) {
  union { float f; unsigned u; } v; v.f = f;
  return (u16)((v.u + 0x7fffu + ((v.u >> 16) & 1u)) >> 16);
}

// ---------------------------------------------------------------- convert
__global__ __launch_bounds__(256) void convert_all(
    const float* __restrict__ x, const float* __restrict__ y,
    const float* __restrict__ wq, const float* __restrict__ wk,
    const float* __restrict__ wv, const float* __restrict__ wp,
    u16* __restrict__ xb, u16* __restrict__ yb,
    u16* __restrict__ wqb, u16* __restrict__ wkb,
    u16* __restrict__ wvb, u16* __restrict__ wpb)
{
  constexpr int G0 = 4096 * 768 / 4;
  constexpr int G1 = G0 + 8192 * 768 / 4;
  constexpr int GW = 768 * 768 / 4;
  int g = blockIdx.x * 256 + threadIdx.x;
  const float* s; u16* d; int o;
  if      (g < G0)          { s = x;  d = xb;  o = g; }
  else if (g < G1)          { s = y;  d = yb;  o = g - G0; }
  else if (g < G1 + GW)     { s = wq; d = wqb; o = g - G1; }
  else if (g < G1 + 2*GW)   { s = wk; d = wkb; o = g - G1 - GW; }
  else if (g < G1 + 3*GW)   { s = wv; d = wvb; o = g - G1 - 2*GW; }
  else if (g < G1 + 4*GW)   { s = wp; d = wpb; o = g - G1 - 3*GW; }
  else return;
  float4 v = reinterpret_cast<const float4*>(s)[o];
  ushort4 r;
  r.x = f2bf(v.x); r.y = f2bf(v.y); r.z = f2bf(v.z); r.w = f2bf(v.w);
  reinterpret_cast<ushort4*>(d)[o] = r;
}

// ---------------------------------------------------------------- GEMM
// C = A @ W^T (both K-contiguous). 128x128 tile, BK=64, 4 waves (2x2).
// Q output is pre-scaled by SCALE*log2(e) so attention logits are already
// in exp2 domain.
template <bool PROJ>
__global__ __launch_bounds__(256) void gemm_k(
    const u16* __restrict__ A0, const u16* __restrict__ A1,
    const u16* __restrict__ W0, const u16* __restrict__ W1,
    const u16* __restrict__ W2,
    u16* __restrict__ Qb, u16* __restrict__ Kb, u16* __restrict__ Vtb,
    const float* __restrict__ bias, float* __restrict__ fout)
{
  __shared__ u16 sA[128 * 64];
  __shared__ u16 sB[128 * 64];

  int bid = blockIdx.x;
  const u16 *A, *W;
  int mode, mt, nt;
  if (PROJ)           { mode = 3; A = A0; W = W0; mt = bid / 6;        nt = bid % 6; }
  else if (bid < 192) { mode = 0; A = A0; W = W0; mt = bid / 6;        nt = bid % 6; }
  else if (bid < 576) { mode = 1; A = A1; W = W1; mt = (bid-192) / 6;  nt = (bid-192) % 6; }
  else                { mode = 2; A = A1; W = W2; mt = (bid-576) / 6;  nt = (bid-576) % 6; }

  const int tid = threadIdx.x;
  const int w = tid >> 6, l = tid & 63;
  const int wm = w >> 1, wn = w & 1;
  const int g = l >> 4, m = l & 15;

  const int mbase = mt * 128, nbase = nt * 128;

  const int srow = l >> 3;
  const int schunk = ((l & 7) ^ srow) * 8;
  const u16* Ag = A + (size_t)(mbase + srow) * 768 + schunk;
  const u16* Wg = W + (size_t)(nbase + srow) * 768 + schunk;

  f32x4 acc[4][4] = {};

  for (int kt = 0; kt < 12; ++kt) {
    __syncthreads();
    const int ko = kt * 64;
#pragma unroll
    for (int i = 0; i < 4; ++i) {
      const int ri = (i * 4 + w) * 8;
      STAGE16(Ag + (size_t)ri * 768 + ko, (char*)sA + ri * 128);
      STAGE16(Wg + (size_t)ri * 768 + ko, (char*)sB + ri * 128);
    }
    __syncthreads();

    bf16x8 af[2][4], bfr[2][4];
#pragma unroll
    for (int c = 0; c < 2; ++c)
#pragma unroll
      for (int t = 0; t < 4; ++t) {
        const int ar = wm * 64 + t * 16 + m;
        const int br = wn * 64 + t * 16 + m;
        const int cp = ((c * 4 + g) ^ (l & 7)) * 16;
        af[c][t]  = *reinterpret_cast<const bf16x8*>((const char*)sA + ar * 128 + cp);
        bfr[c][t] = *reinterpret_cast<const bf16x8*>((const char*)sB + br * 128 + cp);
      }
#pragma unroll
    for (int c = 0; c < 2; ++c)
#pragma unroll
      for (int mi = 0; mi < 4; ++mi)
#pragma unroll
        for (int ni = 0; ni < 4; ++ni)
          acc[mi][ni] = MFMA(af[c][mi], bfr[c][ni], acc[mi][ni]);
  }

  const float QSCALE = 0.18033688011112042f;  // 0.125 * log2(e)
  const int rowb = mbase + wm * 64 + g * 4;
  const int colb = nbase + wn * 64 + m;
#pragma unroll
  for (int mi = 0; mi < 4; ++mi) {
#pragma unroll
    for (int ni = 0; ni < 4; ++ni) {
      const int col = colb + ni * 16;
      const int h = col >> 6, d = col & 63;
      if constexpr (PROJ) {
#pragma unroll
        for (int r = 0; r < 4; ++r) {
          const int row = rowb + mi * 16 + r;
          fout[(size_t)row * 768 + col] = acc[mi][ni][r] + bias[col];
        }
      } else {
        if (mode == 0) {
#pragma unroll
          for (int r = 0; r < 4; ++r) {
            const int row = rowb + mi * 16 + r;
            const int b_ = row >> 10, n = row & 1023;
            Qb[((size_t)(b_ * 12 + h) * 1024 + n) * 64 + d] =
                f2bf(acc[mi][ni][r] * QSCALE);
          }
        } else if (mode == 1) {
#pragma unroll
          for (int r = 0; r < 4; ++r) {
            const int row = rowb + mi * 16 + r;
            const int b_ = row >> 11, n = row & 2047;
            Kb[((size_t)(b_ * 12 + h) * 2048 + n) * 64 + d] = f2bf(acc[mi][ni][r]);
          }
        } else {
          const int row = rowb + mi * 16;
          const int b_ = row >> 11, n = row & 2047;
          ushort4 pk;
          pk.x = f2bf(acc[mi][ni][0]); pk.y = f2bf(acc[mi][ni][1]);
          pk.z = f2bf(acc[mi][ni][2]); pk.w = f2bf(acc[mi][ni][3]);
          *reinterpret_cast<ushort4*>(Vtb + ((size_t)(b_ * 12 + h) * 64 + d) * 2048 + n) = pk;
        }
      }
    }
  }
}

// ---------------------------------------------------------------- attention
// Flash-style. Block = one (b,h) x 64 q-rows; 4 waves, 16 q-rows/wave.
// KVBLK=64. K and V tiles staged cooperatively into LDS (global_load_lds,
// 16B, XOR-swizzled via pre-swizzled global source; linear LDS dest),
// double-buffered: prefetch kt+1 issued before computing kt, one
// __syncthreads per iteration (implicit vmcnt(0) drain covers the DMA).
// Q pre-scaled by SCALE*log2e in the QKV GEMM. Online softmax in exp2
// domain with defer-max (skip O-rescale when max grew < 8).
__global__ __launch_bounds__(256) void attn_fwd(
    const u16* __restrict__ Qb, const u16* __restrict__ Kb,
    const u16* __restrict__ Vtb, u16* __restrict__ AOb)
{
  __shared__ u16 sK[2][64 * 64];
  __shared__ u16 sV[2][64 * 64];
  __shared__ u16 pS[4][16][72];

  const int bid = blockIdx.x;
  const int bh = bid >> 4, qt = bid & 15;
  const int tid = threadIdx.x;
  const int w = tid >> 6, l = tid & 63;
  const int g = l >> 4, m = l & 15;

  const u16* qrow = Qb + ((size_t)bh * 1024 + qt * 64 + w * 16 + m) * 64 + g * 8;
  const bf16x8 aq0 = *reinterpret_cast<const bf16x8*>(qrow);
  const bf16x8 aq1 = *reinterpret_cast<const bf16x8*>(qrow + 32);

  const u16* Kbh = Kb + (size_t)bh * 2048 * 64;
  const u16* Vbh = Vtb + (size_t)bh * 64 * 2048;

  // staging: lane -> row (l>>3) of an 8-row group, swizzled 16B chunk
  const int srow = l >> 3;
  const int soff = ((l & 7) ^ srow) * 8;  // element offset within row

  f32x4 o[4] = {};
  float mrun[4], lrun[4];
#pragma unroll
  for (int r = 0; r < 4; ++r) { mrun[r] = -1e30f; lrun[r] = 0.f; }

  const int r7 = (m & 7);                 // frag-row & 7 (rows are j*16+m)
  const int ck0 = (g ^ r7) * 16;          // swizzled byte chunk, d-lo half
  const int ck1 = ((g + 4) ^ r7) * 16;    // d-hi half

  // prologue stage of tile 0
#pragma unroll
  for (int i = 0; i < 2; ++i) {
    const int rg = w * 16 + i * 8;
    STAGE16(Kbh + (size_t)(rg + srow) * 64 + soff, (char*)&sK[0][0] + rg * 128);
    STAGE16(Vbh + (size_t)(rg + srow) * 2048 + soff, (char*)&sV[0][0] + rg * 128);
  }

  int cur = 0;
  for (int kt = 0; kt < 32; ++kt) {
    __syncthreads();  // staged tile `cur` ready; prev reads of cur^1 done
    if (kt < 31) {
      const int kv1 = (kt + 1) * 64;
#pragma unroll
      for (int i = 0; i < 2; ++i) {
        const int rg = w * 16 + i * 8;
        STAGE16(Kbh + (size_t)(kv1 + rg + srow) * 64 + soff,
                (char*)&sK[cur ^ 1][0] + rg * 128);
        STAGE16(Vbh + (size_t)(rg + srow) * 2048 + kv1 + soff,
                (char*)&sV[cur ^ 1][0] + rg * 128);
      }
    }

    // ---- QK^T from LDS
    const char* sKc = (const char*)&sK[cur][0];
    f32x4 s[4] = {};
#pragma unroll
    for (int j = 0; j < 4; ++j) {
      const int rb = (j * 16 + m) * 128;
      const bf16x8 bk0 = *reinterpret_cast<const bf16x8*>(sKc + rb + ck0);
      const bf16x8 bk1 = *reinterpret_cast<const bf16x8*>(sKc + rb + ck1);
      s[j] = MFMA(aq0, bk0, s[j]);
      s[j] = MFMA(aq1, bk1, s[j]);
    }

    // ---- online softmax (exp2 domain; logits pre-scaled)
    float z[4][4], tmax[4], tsum[4];
#pragma unroll
    for (int r = 0; r < 4; ++r) tmax[r] = -1e30f;
#pragma unroll
    for (int j = 0; j < 4; ++j)
#pragma unroll
      for (int r = 0; r < 4; ++r) {
        z[j][r] = s[j][r];
        tmax[r] = fmaxf(tmax[r], z[j][r]);
      }
#pragma unroll
    for (int dd = 1; dd < 16; dd <<= 1)
#pragma unroll
      for (int r = 0; r < 4; ++r)
        tmax[r] = fmaxf(tmax[r], __shfl_xor(tmax[r], dd));

    bool ok = true;
#pragma unroll
    for (int r = 0; r < 4; ++r) ok &= (tmax[r] <= mrun[r] + 8.f);
    if (!__all(ok)) {
#pragma unroll
      for (int r = 0; r < 4; ++r) {
        const float mn = fmaxf(mrun[r], tmax[r]);
        const float al = exp2f(mrun[r] - mn);
        mrun[r] = mn;
        lrun[r] *= al;
        o[0][r] *= al; o[1][r] *= al; o[2][r] *= al; o[3][r] *= al;
      }
    }
#pragma unroll
    for (int r = 0; r < 4; ++r) tsum[r] = 0.f;
#pragma unroll
    for (int j = 0; j < 4; ++j)
#pragma unroll
      for (int r = 0; r < 4; ++r) {
        const float p = exp2f(z[j][r] - mrun[r]);
        z[j][r] = p;
        tsum[r] += p;
      }
#pragma unroll
    for (int dd = 1; dd < 16; dd <<= 1)
#pragma unroll
      for (int r = 0; r < 4; ++r)
        tsum[r] += __shfl_xor(tsum[r], dd);
#pragma unroll
    for (int r = 0; r < 4; ++r) lrun[r] += tsum[r];

    // ---- P: C-layout -> per-wave LDS -> A-frag layout
#pragma unroll
    for (int j = 0; j < 4; ++j)
#pragma unroll
      for (int r = 0; r < 4; ++r)
        pS[w][g * 4 + r][j * 16 + m] = f2bf(z[j][r]);
    const bf16x8 ap0 = *reinterpret_cast<const bf16x8*>(&pS[w][m][g * 8]);
    const bf16x8 ap1 = *reinterpret_cast<const bf16x8*>(&pS[w][m][32 + g * 8]);

    // ---- O += P @ V from LDS (Vt rows = d)
    const char* sVc = (const char*)&sV[cur][0];
#pragma unroll
    for (int jd = 0; jd < 4; ++jd) {
      const int rb = (jd * 16 + m) * 128;
      const bf16x8 bv0 = *reinterpret_cast<const bf16x8*>(sVc + rb + ck0);
      const bf16x8 bv1 = *reinterpret_cast<const bf16x8*>(sVc + rb + ck1);
      o[jd] = MFMA(ap0, bv0, o[jd]);
      o[jd] = MFMA(ap1, bv1, o[jd]);
    }
    cur ^= 1;
  }

  // ---- epilogue
  const int b_ = bh / 12, h = bh % 12;
  const int q0 = qt * 64 + w * 16 + g * 4;
#pragma unroll
  for (int r = 0; r < 4; ++r) {
    const float rl = 1.f / lrun[r];
#pragma unroll
    for (int jd = 0; jd < 4; ++jd)
      AOb[((size_t)b_ * 1024 + q0 + r) * 768 + h * 64 + jd * 16 + m] =
          f2bf(o[jd][r] * rl);
  }
}

// ---------------------------------------------------------------- launch
extern "C" void kernel_launch(void* const* d_in, const int* in_sizes, int n_in,
                              void* d_out, int out_size, void* d_ws, size_t ws_size,
                              hipStream_t stream)
{
  const float* x  = (const float*)d_in[0];
  const float* y  = (const float*)d_in[1];
  const float* wq = (const float*)d_in[2];
  const float* wk = (const float*)d_in[3];
  const float* wv = (const float*)d_in[4];
  const float* wp = (const float*)d_in[5];
  const float* bp = (const float*)d_in[6];
  float* out = (float*)d_out;

  char* ws = (char*)d_ws;
  u16* xb  = (u16*)ws; ws += (size_t)4096 * 768 * 2;
  u16* yb  = (u16*)ws; ws += (size_t)8192 * 768 * 2;
  u16* wqb = (u16*)ws; ws += (size_t)768 * 768 * 2;
  u16* wkb = (u16*)ws; ws += (size_t)768 * 768 * 2;
  u16* wvb = (u16*)ws; ws += (size_t)768 * 768 * 2;
  u16* wpb = (u16*)ws; ws += (size_t)768 * 768 * 2;
  u16* Qb  = (u16*)ws; ws += (size_t)4096 * 768 * 2;
  u16* Kb  = (u16*)ws; ws += (size_t)8192 * 768 * 2;
  u16* Vtb = (u16*)ws; ws += (size_t)8192 * 768 * 2;
  u16* AOb = (u16*)ws; ws += (size_t)4096 * 768 * 2;

  convert_all<<<11520, 256, 0, stream>>>(x, y, wq, wk, wv, wp,
                                         xb, yb, wqb, wkb, wvb, wpb);
  gemm_k<false><<<960, 256, 0, stream>>>(xb, yb, wqb, wkb, wvb,
                                         Qb, Kb, Vtb, nullptr, nullptr);
  attn_fwd<<<768, 256, 0, stream>>>(Qb, Kb, Vtb, AOb);
  gemm_k<true><<<192, 256, 0, stream>>>(AOb, nullptr, wpb, nullptr, nullptr,
                                        nullptr, nullptr, nullptr, bp, out);
}

// Round 3
// 145.100 us; speedup vs baseline: 1.6928x; 1.1772x over previous
//
#include <hip/hip_runtime.h>
#include <hip/hip_bf16.h>

typedef unsigned short u16;
typedef __attribute__((ext_vector_type(8))) short bf16x8;
typedef __attribute__((ext_vector_type(4))) float f32x4;

#define MFMA(a, b, c) __builtin_amdgcn_mfma_f32_16x16x32_bf16(a, b, c, 0, 0, 0)

#define STAGE16(g, l) __builtin_amdgcn_global_load_lds( \
    (const __attribute__((address_space(1))) void*)(g),  \
    (__attribute__((address_space(3))) void*)(l), 16, 0, 0)

__device__ __forceinline__ u16 f2bf(float f) {
  union { float f; unsigned u; } v; v.f = f;
  return (u16)((v.u + 0x7fffu + ((v.u >> 16) & 1u)) >> 16);
}

__device__ __forceinline__ unsigned pack_bf2(float lo, float hi) {
  __hip_bfloat162 h = __float22bfloat162_rn(float2{lo, hi});
  return *reinterpret_cast<unsigned*>(&h);
}

// ---------------------------------------------------------------- convert
__global__ __launch_bounds__(256) void convert_all(
    const float* __restrict__ x, const float* __restrict__ y,
    const float* __restrict__ wq, const float* __restrict__ wk,
    const float* __restrict__ wv, const float* __restrict__ wp,
    u16* __restrict__ xb, u16* __restrict__ yb,
    u16* __restrict__ wqb, u16* __restrict__ wkb,
    u16* __restrict__ wvb, u16* __restrict__ wpb)
{
  constexpr int G0 = 4096 * 768 / 4;
  constexpr int G1 = G0 + 8192 * 768 / 4;
  constexpr int GW = 768 * 768 / 4;
  int g = blockIdx.x * 256 + threadIdx.x;
  const float* s; u16* d; int o;
  if      (g < G0)          { s = x;  d = xb;  o = g; }
  else if (g < G1)          { s = y;  d = yb;  o = g - G0; }
  else if (g < G1 + GW)     { s = wq; d = wqb; o = g - G1; }
  else if (g < G1 + 2*GW)   { s = wk; d = wkb; o = g - G1 - GW; }
  else if (g < G1 + 3*GW)   { s = wv; d = wvb; o = g - G1 - 2*GW; }
  else if (g < G1 + 4*GW)   { s = wp; d = wpb; o = g - G1 - 3*GW; }
  else return;
  float4 v = reinterpret_cast<const float4*>(s)[o];
  ushort4 r;
  r.x = f2bf(v.x); r.y = f2bf(v.y); r.z = f2bf(v.z); r.w = f2bf(v.w);
  reinterpret_cast<ushort4*>(d)[o] = r;
}

// ---------------------------------------------------------------- GEMM
// C = A @ W^T (both K-contiguous). 128x128 tile, BK=64, 4 waves (2x2).
// Q output pre-scaled by SCALE*log2(e) (attention logits in exp2 domain).
template <bool PROJ>
__global__ __launch_bounds__(256) void gemm_k(
    const u16* __restrict__ A0, const u16* __restrict__ A1,
    const u16* __restrict__ W0, const u16* __restrict__ W1,
    const u16* __restrict__ W2,
    u16* __restrict__ Qb, u16* __restrict__ Kb, u16* __restrict__ Vtb,
    const float* __restrict__ bias, float* __restrict__ fout)
{
  __shared__ u16 sA[128 * 64];
  __shared__ u16 sB[128 * 64];

  int bid = blockIdx.x;
  const u16 *A, *W;
  int mode, mt, nt;
  if (PROJ)           { mode = 3; A = A0; W = W0; mt = bid / 6;        nt = bid % 6; }
  else if (bid < 192) { mode = 0; A = A0; W = W0; mt = bid / 6;        nt = bid % 6; }
  else if (bid < 576) { mode = 1; A = A1; W = W1; mt = (bid-192) / 6;  nt = (bid-192) % 6; }
  else                { mode = 2; A = A1; W = W2; mt = (bid-576) / 6;  nt = (bid-576) % 6; }

  const int tid = threadIdx.x;
  const int w = tid >> 6, l = tid & 63;
  const int wm = w >> 1, wn = w & 1;
  const int g = l >> 4, m = l & 15;

  const int mbase = mt * 128, nbase = nt * 128;

  const int srow = l >> 3;
  const int schunk = ((l & 7) ^ srow) * 8;
  const u16* Ag = A + (size_t)(mbase + srow) * 768 + schunk;
  const u16* Wg = W + (size_t)(nbase + srow) * 768 + schunk;

  f32x4 acc[4][4] = {};

  for (int kt = 0; kt < 12; ++kt) {
    __syncthreads();
    const int ko = kt * 64;
#pragma unroll
    for (int i = 0; i < 4; ++i) {
      const int ri = (i * 4 + w) * 8;
      STAGE16(Ag + (size_t)ri * 768 + ko, (char*)sA + ri * 128);
      STAGE16(Wg + (size_t)ri * 768 + ko, (char*)sB + ri * 128);
    }
    __syncthreads();

    bf16x8 af[2][4], bfr[2][4];
#pragma unroll
    for (int c = 0; c < 2; ++c)
#pragma unroll
      for (int t = 0; t < 4; ++t) {
        const int ar = wm * 64 + t * 16 + m;
        const int br = wn * 64 + t * 16 + m;
        const int cp = ((c * 4 + g) ^ (l & 7)) * 16;
        af[c][t]  = *reinterpret_cast<const bf16x8*>((const char*)sA + ar * 128 + cp);
        bfr[c][t] = *reinterpret_cast<const bf16x8*>((const char*)sB + br * 128 + cp);
      }
#pragma unroll
    for (int c = 0; c < 2; ++c)
#pragma unroll
      for (int mi = 0; mi < 4; ++mi)
#pragma unroll
        for (int ni = 0; ni < 4; ++ni)
          acc[mi][ni] = MFMA(af[c][mi], bfr[c][ni], acc[mi][ni]);
  }

  const float QSCALE = 0.18033688011112042f;  // 0.125 * log2(e)
  const int rowb = mbase + wm * 64 + g * 4;
  const int colb = nbase + wn * 64 + m;
#pragma unroll
  for (int mi = 0; mi < 4; ++mi) {
#pragma unroll
    for (int ni = 0; ni < 4; ++ni) {
      const int col = colb + ni * 16;
      const int h = col >> 6, d = col & 63;
      if constexpr (PROJ) {
#pragma unroll
        for (int r = 0; r < 4; ++r) {
          const int row = rowb + mi * 16 + r;
          fout[(size_t)row * 768 + col] = acc[mi][ni][r] + bias[col];
        }
      } else {
        if (mode == 0) {
#pragma unroll
          for (int r = 0; r < 4; ++r) {
            const int row = rowb + mi * 16 + r;
            const int b_ = row >> 10, n = row & 1023;
            Qb[((size_t)(b_ * 12 + h) * 1024 + n) * 64 + d] =
                f2bf(acc[mi][ni][r] * QSCALE);
          }
        } else if (mode == 1) {
#pragma unroll
          for (int r = 0; r < 4; ++r) {
            const int row = rowb + mi * 16 + r;
            const int b_ = row >> 11, n = row & 2047;
            Kb[((size_t)(b_ * 12 + h) * 2048 + n) * 64 + d] = f2bf(acc[mi][ni][r]);
          }
        } else {
          const int row = rowb + mi * 16;
          const int b_ = row >> 11, n = row & 2047;
          ushort4 pk;
          pk.x = f2bf(acc[mi][ni][0]); pk.y = f2bf(acc[mi][ni][1]);
          pk.z = f2bf(acc[mi][ni][2]); pk.w = f2bf(acc[mi][ni][3]);
          *reinterpret_cast<ushort4*>(Vtb + ((size_t)(b_ * 12 + h) * 64 + d) * 2048 + n) = pk;
        }
      }
    }
  }
}

// ---------------------------------------------------------------- attention
// Flash-style, swapped QK^T (T12): s = MFMA(K,Q) -> S^T, col = q = lane&15,
// rows = kv. Each lane owns a full 64-kv slice view of ONE q row:
// 16 in-lane values + lanes {m,m+16,m+32,m+48} hold disjoint kv quarters ->
// row reduce = 15 in-lane ops + 2 shfl_xor. m/l stats are per-lane scalars.
// P packed with v_cvt_pk_bf16_f32 pairs (adjacent kv = adjacent regs),
// 4x ds_write_b64 -> pS[16 q][36 words] (144B stride) -> 2x ds_read_b128
// gives the PV A-fragment. O keeps the normal C-layout (q=g*4+r), so
// deferred rescale / epilogue fetch per-row alpha/l via 4 bpermutes.
// K/V staged via global_load_lds (16B, XOR-swizzled source), double-buffered.
// Grid swizzled so all 16 q-tiles of one head share an XCD (L2 locality).
__global__ __launch_bounds__(256) void attn_fwd(
    const u16* __restrict__ Qb, const u16* __restrict__ Kb,
    const u16* __restrict__ Vtb, u16* __restrict__ AOb)
{
  __shared__ u16 sK[2][64 * 64];
  __shared__ u16 sV[2][64 * 64];
  __shared__ unsigned pS[4][16][36];

  const int bid = blockIdx.x;
  const int bh = bid % 48, qt = bid / 48;   // XCD swizzle: head -> one XCD
  const int tid = threadIdx.x;
  const int w = tid >> 6, l = tid & 63;
  const int g = l >> 4, m = l & 15;

  const u16* qrow = Qb + ((size_t)bh * 1024 + qt * 64 + w * 16 + m) * 64 + g * 8;
  const bf16x8 aq0 = *reinterpret_cast<const bf16x8*>(qrow);
  const bf16x8 aq1 = *reinterpret_cast<const bf16x8*>(qrow + 32);

  const u16* Kbh = Kb + (size_t)bh * 2048 * 64;
  const u16* Vbh = Vtb + (size_t)bh * 64 * 2048;

  const int srow = l >> 3;
  const int soff = ((l & 7) ^ srow) * 8;

  f32x4 o[4] = {};
  float mrun = -1e30f, lrun = 0.f;

  const int r7 = (m & 7);
  const int ck0 = (g ^ r7) * 16;
  const int ck1 = ((g + 4) ^ r7) * 16;

#pragma unroll
  for (int i = 0; i < 2; ++i) {
    const int rg = w * 16 + i * 8;
    STAGE16(Kbh + (size_t)(rg + srow) * 64 + soff, (char*)&sK[0][0] + rg * 128);
    STAGE16(Vbh + (size_t)(rg + srow) * 2048 + soff, (char*)&sV[0][0] + rg * 128);
  }

  int cur = 0;
  for (int kt = 0; kt < 32; ++kt) {
    __syncthreads();
    if (kt < 31) {
      const int kv1 = (kt + 1) * 64;
#pragma unroll
      for (int i = 0; i < 2; ++i) {
        const int rg = w * 16 + i * 8;
        STAGE16(Kbh + (size_t)(kv1 + rg + srow) * 64 + soff,
                (char*)&sK[cur ^ 1][0] + rg * 128);
        STAGE16(Vbh + (size_t)(rg + srow) * 2048 + kv1 + soff,
                (char*)&sV[cur ^ 1][0] + rg * 128);
      }
    }

    // ---- S^T = K @ Q^T from LDS (swapped operands)
    const char* sKc = (const char*)&sK[cur][0];
    f32x4 s[4] = {};
    __builtin_amdgcn_s_setprio(1);
#pragma unroll
    for (int j = 0; j < 4; ++j) {
      const int rb = (j * 16 + m) * 128;
      const bf16x8 bk0 = *reinterpret_cast<const bf16x8*>(sKc + rb + ck0);
      const bf16x8 bk1 = *reinterpret_cast<const bf16x8*>(sKc + rb + ck1);
      s[j] = MFMA(bk0, aq0, s[j]);
      s[j] = MFMA(bk1, aq1, s[j]);
    }
    __builtin_amdgcn_s_setprio(0);

    // ---- online softmax: lane owns q = w*16+m; kv = j*16 + g*4 + r
    float tmax = s[0][0];
#pragma unroll
    for (int j = 0; j < 4; ++j)
#pragma unroll
      for (int r = 0; r < 4; ++r)
        if (j | r) tmax = fmaxf(tmax, s[j][r]);
    tmax = fmaxf(tmax, __shfl_xor(tmax, 16));
    tmax = fmaxf(tmax, __shfl_xor(tmax, 32));

    if (!__all(tmax <= mrun + 8.f)) {
      const float mn = fmaxf(mrun, tmax);
      const float al = exp2f(mrun - mn);
      mrun = mn;
      lrun *= al;
      float alr[4];
#pragma unroll
      for (int r = 0; r < 4; ++r) alr[r] = __shfl(al, g * 4 + r);
#pragma unroll
      for (int jd = 0; jd < 4; ++jd) {
        f32x4 t = o[jd];
        t[0] *= alr[0]; t[1] *= alr[1]; t[2] *= alr[2]; t[3] *= alr[3];
        o[jd] = t;
      }
    }

    float tsum = 0.f;
    float z[4][4];
#pragma unroll
    for (int j = 0; j < 4; ++j)
#pragma unroll
      for (int r = 0; r < 4; ++r) {
        const float p = exp2f(s[j][r] - mrun);
        z[j][r] = p;
        tsum += p;
      }
    tsum += __shfl_xor(tsum, 16);
    tsum += __shfl_xor(tsum, 32);
    lrun += tsum;

    // ---- P pack: pS[q=m][word j*8+g*2 .. +1] via cvt_pk pairs
#pragma unroll
    for (int j = 0; j < 4; ++j) {
      uint2 pw;
      pw.x = pack_bf2(z[j][0], z[j][1]);
      pw.y = pack_bf2(z[j][2], z[j][3]);
      *reinterpret_cast<uint2*>(&pS[w][m][j * 8 + g * 2]) = pw;
    }
    const bf16x8 ap0 = *reinterpret_cast<const bf16x8*>(&pS[w][m][g * 4]);
    const bf16x8 ap1 = *reinterpret_cast<const bf16x8*>(&pS[w][m][16 + g * 4]);

    // ---- O += P @ V from LDS
    const char* sVc = (const char*)&sV[cur][0];
    __builtin_amdgcn_s_setprio(1);
#pragma unroll
    for (int jd = 0; jd < 4; ++jd) {
      const int rb = (jd * 16 + m) * 128;
      const bf16x8 bv0 = *reinterpret_cast<const bf16x8*>(sVc + rb + ck0);
      const bf16x8 bv1 = *reinterpret_cast<const bf16x8*>(sVc + rb + ck1);
      o[jd] = MFMA(ap0, bv0, o[jd]);
      o[jd] = MFMA(ap1, bv1, o[jd]);
    }
    __builtin_amdgcn_s_setprio(0);
    cur ^= 1;
  }

  // ---- epilogue: per-row l via bpermute (lane q holds l for q = lane&15)
  float lq[4];
#pragma unroll
  for (int r = 0; r < 4; ++r) lq[r] = __shfl(lrun, g * 4 + r);

  const int b_ = bh / 12, h = bh % 12;
  const int q0 = qt * 64 + w * 16 + g * 4;
#pragma unroll
  for (int r = 0; r < 4; ++r) {
    const float rl = 1.f / lq[r];
#pragma unroll
    for (int jd = 0; jd < 4; ++jd)
      AOb[((size_t)b_ * 1024 + q0 + r) * 768 + h * 64 + jd * 16 + m] =
          f2bf(o[jd][r] * rl);
  }
}

// ---------------------------------------------------------------- launch
extern "C" void kernel_launch(void* const* d_in, const int* in_sizes, int n_in,
                              void* d_out, int out_size, void* d_ws, size_t ws_size,
                              hipStream_t stream)
{
  const float* x  = (const float*)d_in[0];
  const float* y  = (const float*)d_in[1];
  const float* wq = (const float*)d_in[2];
  const float* wk = (const float*)d_in[3];
  const float* wv = (const float*)d_in[4];
  const float* wp = (const float*)d_in[5];
  const float* bp = (const float*)d_in[6];
  float* out = (float*)d_out;

  char* ws = (char*)d_ws;
  u16* xb  = (u16*)ws; ws += (size_t)4096 * 768 * 2;
  u16* yb  = (u16*)ws; ws += (size_t)8192 * 768 * 2;
  u16* wqb = (u16*)ws; ws += (size_t)768 * 768 * 2;
  u16* wkb = (u16*)ws; ws += (size_t)768 * 768 * 2;
  u16* wvb = (u16*)ws; ws += (size_t)768 * 768 * 2;
  u16* wpb = (u16*)ws; ws += (size_t)768 * 768 * 2;
  u16* Qb  = (u16*)ws; ws += (size_t)4096 * 768 * 2;
  u16* Kb  = (u16*)ws; ws += (size_t)8192 * 768 * 2;
  u16* Vtb = (u16*)ws; ws += (size_t)8192 * 768 * 2;
  u16* AOb = (u16*)ws; ws += (size_t)4096 * 768 * 2;

  convert_all<<<11520, 256, 0, stream>>>(x, y, wq, wk, wv, wp,
                                         xb, yb, wqb, wkb, wvb, wpb);
  gemm_k<false><<<960, 256, 0, stream>>>(xb, yb, wqb, wkb, wvb,
                                         Qb, Kb, Vtb, nullptr, nullptr);
  attn_fwd<<<768, 256, 0, stream>>>(Qb, Kb, Vtb, AOb);
  gemm_k<true><<<192, 256, 0, stream>>>(AOb, nullptr, wpb, nullptr, nullptr,
                                        nullptr, nullptr, nullptr, bp, out);
}